// Round 1
// baseline (1511.834 us; speedup 1.0000x reference)
//
#include <hip/hip_runtime.h>
#include <cstddef>

// ---------------------------------------------------------------------------
// STPGCN forward, f32. B=8 T=12 V=512 C=128 d=8 TSZ=3 L=3 P=12
// Decomposition: S[b,t,j,k,i] = E[b,t]*F[b,t,k]*W[j,k,i]  (W per-layer, bt-independent)
// ---------------------------------------------------------------------------

#define BB 8
#define TT 12
#define VV 512
#define CC 128
#define DD 8

__device__ __forceinline__ float sigmoidf_(float x){ return 1.0f/(1.0f+expf(-x)); }

__device__ __forceinline__ float gauss8(const float* __restrict__ e,
                                        const float* __restrict__ mu,
                                        const float* __restrict__ sg){
  float a = 0.f;
  #pragma unroll
  for (int dd=0; dd<8; ++dd){
    float df = e[dd]-mu[dd];
    float s  = sg[dd];
    a = fmaf(-0.5f*df*df, s*s, a);
  }
  return a;
}

// ---------------- weight transposes (once per call) ----------------
__global__ __launch_bounds__(256) void k_prep(
    const float* __restrict__ fs0_fc_w, const float* __restrict__ fs_fc_w,
    const float* __restrict__ fs0_glu_w, const float* __restrict__ fs_glu_w,
    const float* __restrict__ glu_w, const float* __restrict__ out_w,
    float* __restrict__ fwT, float* __restrict__ gwT,
    float* __restrict__ gluT, float* __restrict__ outT){
  int job = blockIdx.y;
  int gid = blockIdx.x*256 + threadIdx.x;
  if (job < 4){                       // fw (128, 12*128) -> fwT[t*128+c][o]
    if (gid >= 196608) return;
    const float* src = (job==0) ? fs0_fc_w : fs_fc_w + (size_t)(job-1)*196608;
    float* dst = fwT + (size_t)job*196608;
    int r = gid / 1536, c = gid % 1536;
    dst[(size_t)c*128 + r] = src[gid];
  } else if (job < 8){                // gw (256,128) -> gwT[o][p]
    if (gid >= 32768) return;
    int sl = job-4;
    const float* src = (sl==0) ? fs0_glu_w : fs_glu_w + (size_t)(sl-1)*32768;
    float* dst = gwT + (size_t)sl*32768;
    int r = gid / 128, c = gid % 128;
    dst[(size_t)c*256 + r] = src[gid];
  } else if (job == 8){               // glu_w (1024,512) -> gluT[o][p]
    if (gid >= 524288) return;
    int r = gid / 512, c = gid % 512;
    gluT[(size_t)c*1024 + r] = glu_w[gid];
  } else {                            // out_w (12,512) -> outT[q][r]
    if (gid >= 6144) return;
    int r = gid / 512, c = gid % 512;
    outT[(size_t)c*12 + r] = out_w[gid];
  }
}

// ---------------- input layer: h = x*iw + ib ----------------
__global__ __launch_bounds__(256) void k_input(const float* __restrict__ x,
    const float* __restrict__ iw, const float* __restrict__ ib, float* __restrict__ h){
  int gid = blockIdx.x*256 + threadIdx.x;
  if (gid >= BB*TT*VV*CC) return;
  int c = gid & 127; int r = gid >> 7;
  h[gid] = fmaf(x[r], iw[c], ib[c]);
}

// ---------------- GFS phase 1: s_part[ts][b][o][v] ----------------
// s[b,o,v] = sum_{t,c} h[b,t,v,c]*fw[o,t,c]   (split over ts: 3 t's each)
__global__ __launch_bounds__(256) void k_gfs1(const float* __restrict__ h,
    const float* __restrict__ fwT, float* __restrict__ s_part){
  int vt = blockIdx.x, b = blockIdx.y, ts = blockIdx.z;
  int tid = threadIdx.x;
  int v0 = vt*64;
  __shared__ float hT[32][68];        // [c-in-chunk][v], padded
  int vtt = tid & 7;                  // 8 v-threads * 8 v
  int ot  = tid >> 3;                 // 32 o-threads * 4 o
  float acc[4][8];
  #pragma unroll
  for (int a=0;a<4;++a)
    #pragma unroll
    for (int u=0;u<8;++u) acc[a][u] = 0.f;

  for (int tt=0; tt<3; ++tt){
    int t = ts*3 + tt;
    const float* hbase = h + ((size_t)(b*TT+t)*VV)*CC;
    for (int cch=0; cch<4; ++cch){
      int c0 = cch*32;
      __syncthreads();
      #pragma unroll
      for (int r=0; r<2; ++r){
        int q = r*256 + tid;
        int vv = q>>3, cc4 = q&7;
        float4 val = *(const float4*)(hbase + (size_t)(v0+vv)*CC + c0 + cc4*4);
        hT[cc4*4+0][vv]=val.x; hT[cc4*4+1][vv]=val.y;
        hT[cc4*4+2][vv]=val.z; hT[cc4*4+3][vv]=val.w;
      }
      __syncthreads();
      const float* fwb = fwT + ((size_t)t*128 + c0)*128 + ot*4;
      for (int c=0;c<32;++c){
        float wv[4], hv[8];
        *(float4*)wv     = *(const float4*)(fwb + (size_t)c*128);
        *(float4*)hv     = *(const float4*)&hT[c][vtt*8];
        *(float4*)(hv+4) = *(const float4*)&hT[c][vtt*8+4];
        #pragma unroll
        for (int a=0;a<4;++a)
          #pragma unroll
          for (int u=0;u<8;++u) acc[a][u] = fmaf(wv[a], hv[u], acc[a][u]);
      }
    }
  }
  float* sp = s_part + (((size_t)ts*BB+b)*128 + ot*4)*VV + v0 + vtt*8;
  #pragma unroll
  for (int a=0;a<4;++a){
    *(float4*)(sp + (size_t)a*VV)     = *(float4*)&acc[a][0];
    *(float4*)(sp + (size_t)a*VV + 4) = *(float4*)&acc[a][4];
  }
}

// ---------------- GFS phase 2: skip -> hc[b][slot*128+o][v] ----------------
__global__ __launch_bounds__(256) void k_gfs2(const float* __restrict__ s_part,
    const float* __restrict__ fb, const float* __restrict__ gwT,
    const float* __restrict__ gb, float* __restrict__ hc, int slot){
  int vt = blockIdx.x, b = blockIdx.y;
  int v0 = vt*32; int tid = threadIdx.x;
  __shared__ float sL[128][36];
  for (int u=0;u<16;++u){
    int lid = u*256 + tid; int o = lid>>5, vv = lid&31;
    float sum = fb[o];
    #pragma unroll
    for (int sp=0;sp<4;++sp)
      sum += s_part[(((size_t)sp*BB+b)*128 + o)*VV + v0 + vv];
    sL[o][vv] = sum;
  }
  __syncthreads();
  int oo = tid & 127, vg = tid >> 7;
  float accL[16], accR[16];
  #pragma unroll
  for (int u=0;u<16;++u){ accL[u]=0.f; accR[u]=0.f; }
  for (int op=0; op<128; ++op){
    float glv = gwT[(size_t)op*256 + oo];
    float grv = gwT[(size_t)op*256 + 128 + oo];
    float sv[16];
    #pragma unroll
    for (int q=0;q<4;++q) *(float4*)(sv+q*4) = *(const float4*)&sL[op][vg*16 + q*4];
    #pragma unroll
    for (int u=0;u<16;++u){ accL[u]=fmaf(glv,sv[u],accL[u]); accR[u]=fmaf(grv,sv[u],accR[u]); }
  }
  float bl = gb[oo], br = gb[128+oo];
  float outv[16];
  #pragma unroll
  for (int u=0;u<16;++u) outv[u] = (accL[u]+bl)*sigmoidf_(accR[u]+br);
  float* dst = hc + ((size_t)b*512 + slot*128 + oo)*VV + v0 + vg*16;
  #pragma unroll
  for (int q=0;q<4;++q) *(float4*)(dst+q*4) = *(float4*)(outv+q*4);
}

// ---------------- per-layer small gaussians ----------------
__global__ void k_smalls(const float* __restrict__ sape, const float* __restrict__ tape,
    const float* __restrict__ trpe, const float* __restrict__ mus,
    const float* __restrict__ isgs, int l,
    float* __restrict__ gi, float* __restrict__ gj,
    float* __restrict__ E, float* __restrict__ F, float* __restrict__ gtr){
  int tid = threadIdx.x;
  const float* mu = mus  + (size_t)l*48;
  const float* sg = isgs + (size_t)l*48;
  if (tid < 512){
    const float* e = sape + (size_t)tid*8;
    gi[tid] = gauss8(e, mu+0,  sg+0);
    gj[tid] = gauss8(e, mu+8,  sg+8);
  }
  if (tid < 96)
    E[tid] = expf(gauss8(tape + (size_t)tid*8, mu+16, sg+16));
  if (tid < 288){
    int k = tid % 3, bt = tid / 3;
    int t = bt % TT, b = bt / TT;
    int s = t + k - 2;
    F[tid] = (s >= 0) ? expf(gauss8(tape + (size_t)(b*TT+s)*8, mu+24, sg+24)) : 0.f;
  }
  if (tid < 3)
    gtr[tid] = gauss8(trpe + (size_t)tid*8, mu+40, sg+40);
}

// ---------------- W[k][i][j] = mask[j,k,i]*exp(gi[i]+gj[j]+gtr[k]+ge[i,j]) ----
__global__ __launch_bounds__(256) void k_W(const float* __restrict__ srpe,
    const float* __restrict__ mask, const float* __restrict__ mus,
    const float* __restrict__ isgs, int l,
    const float* __restrict__ gi, const float* __restrict__ gj,
    const float* __restrict__ gtr, float* __restrict__ W){
  int gid = blockIdx.x*256 + threadIdx.x;     // < 262144
  int i = gid >> 9, j = gid & 511;
  const float* mu = mus  + (size_t)l*48 + 32;
  const float* sg = isgs + (size_t)l*48 + 32;
  float ge = gauss8(srpe + (size_t)gid*8, mu, sg);
  float base = gi[i] + gj[j] + ge;
  float g0 = gtr[0], g1 = gtr[1], g2 = gtr[2];
  W[((size_t)0*VV + i)*VV + j] = mask[(size_t)j*1536 +   0 + i] * expf(base + g0);
  W[((size_t)1*VV + i)*VV + j] = mask[(size_t)j*1536 + 512 + i] * expf(base + g1);
  W[((size_t)2*VV + i)*VV + j] = mask[(size_t)j*1536 +1024 + i] * expf(base + g2);
}

// ---------------- STPGConv GEMM: agg[bt][j][c] = E*sum_k F_k*(W_k h_s) --------
__global__ __launch_bounds__(256) void k_stpg(const float* __restrict__ h,
    const float* __restrict__ W, const float* __restrict__ E,
    const float* __restrict__ F, float* __restrict__ agg){
  int bt = blockIdx.x; int b = bt / TT, t = bt % TT;
  int j0 = blockIdx.y * 64;
  int tid = threadIdx.x;
  __shared__ float Wl[32][64];
  __shared__ float hl[32][128];
  int jt = tid & 15, ct = tid >> 4;
  float acc[4][8];
  #pragma unroll
  for (int a=0;a<4;++a)
    #pragma unroll
    for (int u=0;u<8;++u) acc[a][u]=0.f;

  for (int k=0;k<3;++k){
    int s = t + k - 2;
    if (s < 0) continue;
    float fk = F[bt*3 + k];
    const float* hb = h + ((size_t)(b*TT+s)*VV)*CC;
    const float* Wb = W + ((size_t)k*VV)*VV;
    for (int ic=0; ic<16; ++ic){
      int i0 = ic*32;
      __syncthreads();
      #pragma unroll
      for (int r=0;r<2;++r){
        int q = r*256 + tid; int ii = q>>4, jj4 = q&15;
        float4 wv = *(const float4*)(Wb + (size_t)(i0+ii)*VV + j0 + jj4*4);
        float4 sv; sv.x=wv.x*fk; sv.y=wv.y*fk; sv.z=wv.z*fk; sv.w=wv.w*fk;
        *(float4*)&Wl[ii][jj4*4] = sv;
      }
      #pragma unroll
      for (int r=0;r<4;++r){
        int q = r*256 + tid; int ii = q>>5, cc4 = q&31;
        *(float4*)&hl[ii][cc4*4] = *(const float4*)(hb + (size_t)(i0+ii)*CC + cc4*4);
      }
      __syncthreads();
      for (int ii=0; ii<32; ++ii){
        float wv[4], hv[8];
        *(float4*)wv     = *(const float4*)&Wl[ii][jt*4];
        *(float4*)hv     = *(const float4*)&hl[ii][ct*8];
        *(float4*)(hv+4) = *(const float4*)&hl[ii][ct*8+4];
        #pragma unroll
        for (int a=0;a<4;++a)
          #pragma unroll
          for (int u=0;u<8;++u) acc[a][u] = fmaf(wv[a], hv[u], acc[a][u]);
      }
    }
  }
  float Eb = E[bt];
  #pragma unroll
  for (int a=0;a<4;++a){
    float ov[8];
    #pragma unroll
    for (int u=0;u<8;++u) ov[u] = acc[a][u]*Eb;
    float* dst = agg + ((size_t)bt*VV + j0 + jt*4 + a)*CC + ct*8;
    *(float4*)dst     = *(float4*)&ov[0];
    *(float4*)(dst+4) = *(float4*)&ov[4];
  }
}

// ---------------- xproj + SE/TE proj + LayerNorm + GLU (in place) ------------
__global__ __launch_bounds__(256) void k_xln(float* __restrict__ hB,
    const float* __restrict__ xw, const float* __restrict__ xb,
    const float* __restrict__ sw, const float* __restrict__ tw,
    const float* __restrict__ sape, const float* __restrict__ tape,
    const float* __restrict__ lng, const float* __restrict__ lnb, int l){
  int v0 = blockIdx.x * 8;
  int bt = blockIdx.y;
  int tid = threadIdx.x;                 // p = tid in [0,256)
  __shared__ float aL[8][128];
  __shared__ float se[8][8];
  __shared__ float te[8];
  __shared__ float zL[8][260];
  __shared__ float stat[8][2];
  float* hrow = hB + ((size_t)bt*VV + v0)*CC;
  { int vv = tid>>5, cc4 = tid&31;
    *(float4*)&aL[vv][cc4*4] = *(const float4*)(hrow + (size_t)vv*CC + cc4*4); }
  if (tid < 64) se[tid>>3][tid&7] = sape[(size_t)(v0 + (tid>>3))*8 + (tid&7)];
  if (tid >= 64 && tid < 72) te[tid-64] = tape[(size_t)bt*8 + (tid-64)];
  __syncthreads();

  const float* xwl = xw + (size_t)l*32768;
  const float* swl = sw + (size_t)l*2048;
  const float* twl = tw + (size_t)l*2048;
  float common = xb[l*256 + tid];
  #pragma unroll
  for (int dd=0; dd<8; ++dd) common = fmaf(te[dd], twl[dd*256+tid], common);
  float z[8];
  #pragma unroll
  for (int vv=0; vv<8; ++vv){
    float sacc = common;
    #pragma unroll
    for (int dd=0; dd<8; ++dd) sacc = fmaf(se[vv][dd], swl[dd*256+tid], sacc);
    z[vv] = sacc;
  }
  for (int c4=0; c4<32; ++c4){
    float x0 = xwl[(c4*4+0)*256 + tid];
    float x1 = xwl[(c4*4+1)*256 + tid];
    float x2 = xwl[(c4*4+2)*256 + tid];
    float x3 = xwl[(c4*4+3)*256 + tid];
    #pragma unroll
    for (int vv=0; vv<8; ++vv){
      float4 a4 = *(const float4*)&aL[vv][c4*4];
      z[vv] = fmaf(a4.x,x0, fmaf(a4.y,x1, fmaf(a4.z,x2, fmaf(a4.w,x3, z[vv]))));
    }
  }
  #pragma unroll
  for (int vv=0; vv<8; ++vv) zL[vv][tid] = z[vv];
  __syncthreads();
  { int vv = tid>>5, sub = tid&31;
    float s1=0.f, s2=0.f;
    #pragma unroll
    for (int u=0; u<8; ++u){ float val = zL[vv][sub + u*32]; s1 += val; s2 = fmaf(val,val,s2); }
    #pragma unroll
    for (int off=16; off>=1; off>>=1){
      s1 += __shfl_down(s1, off, 32);
      s2 += __shfl_down(s2, off, 32);
    }
    if (sub==0){
      float mn = s1*(1.f/256.f);
      float var = s2*(1.f/256.f) - mn*mn;
      stat[vv][0] = mn;
      stat[vv][1] = 1.f/sqrtf(var + 1e-5f);
    }
  }
  __syncthreads();
  { int vv = tid>>5, sub = tid&31;
    float mn = stat[vv][0], rs = stat[vv][1];
    float4 zl = *(const float4*)&zL[vv][sub*4];
    float4 zr = *(const float4*)&zL[vv][sub*4+128];
    float zlv[4] = {zl.x,zl.y,zl.z,zl.w};
    float zrv[4] = {zr.x,zr.y,zr.z,zr.w};
    float ov[4];
    #pragma unroll
    for (int u=0; u<4; ++u){
      int c = sub*4 + u;
      float nl = (zlv[u]-mn)*rs*lng[l*256 + c]       + lnb[l*256 + c];
      float nr = (zrv[u]-mn)*rs*lng[l*256 + 128 + c] + lnb[l*256 + 128 + c];
      ov[u] = nl * sigmoidf_(nr);
    }
    *(float4*)(hrow + (size_t)vv*CC + sub*4) = *(float4*)ov;
  }
}

// ---------------- final GLU + out ----------------
__global__ __launch_bounds__(256) void k_final(const float* __restrict__ hc,
    const float* __restrict__ gluT, const float* __restrict__ glub,
    const float* __restrict__ outT, const float* __restrict__ outb,
    float* __restrict__ out){
  int b = blockIdx.y; int v0 = blockIdx.x * 8;
  int tid = threadIdx.x;
  __shared__ float hcl[512][8];
  __shared__ float gl[512][9];
  for (int u=0; u<16; ++u){
    int lid = u*256 + tid; int o = lid>>3, vv = lid&7;
    hcl[o][vv] = hc[((size_t)b*512 + o)*VV + v0 + vv];
  }
  __syncthreads();
  float aL0[8], aR0[8], aL1[8], aR1[8];
  #pragma unroll
  for (int u=0;u<8;++u){ aL0[u]=0.f; aR0[u]=0.f; aL1[u]=0.f; aR1[u]=0.f; }
  for (int o=0; o<512; ++o){
    const float* grow = gluT + (size_t)o*1024;
    float g0 = grow[tid], g1 = grow[tid+256], g2 = grow[tid+512], g3 = grow[tid+768];
    float hv[8];
    *(float4*)hv     = *(const float4*)&hcl[o][0];
    *(float4*)(hv+4) = *(const float4*)&hcl[o][4];
    #pragma unroll
    for (int u=0;u<8;++u){
      aL0[u]=fmaf(g0,hv[u],aL0[u]); aL1[u]=fmaf(g1,hv[u],aL1[u]);
      aR0[u]=fmaf(g2,hv[u],aR0[u]); aR1[u]=fmaf(g3,hv[u],aR1[u]);
    }
  }
  float bL0 = glub[tid], bL1 = glub[tid+256], bR0 = glub[tid+512], bR1 = glub[tid+768];
  #pragma unroll
  for (int u=0;u<8;++u){
    gl[tid][u]     = (aL0[u]+bL0)*sigmoidf_(aR0[u]+bR0);
    gl[tid+256][u] = (aL1[u]+bL1)*sigmoidf_(aR1[u]+bR1);
  }
  __syncthreads();
  if (tid < 96){
    int r = tid>>3, vv = tid&7;
    float acc = outb[r];
    for (int q=0; q<512; ++q) acc = fmaf(outT[(size_t)q*12 + r], gl[q][vv], acc);
    out[(size_t)b*6144 + r*512 + v0 + vv] = acc;
  }
}

// ---------------------------------------------------------------------------
extern "C" void kernel_launch(void* const* d_in, const int* in_sizes, int n_in,
                              void* d_out, int out_size, void* d_ws, size_t ws_size,
                              hipStream_t stream){
  const float* x        = (const float*)d_in[0];
  const float* sape     = (const float*)d_in[1];
  const float* tape     = (const float*)d_in[2];
  const float* srpe     = (const float*)d_in[3];
  const float* trpe     = (const float*)d_in[4];
  const float* mask     = (const float*)d_in[7];
  const float* input_w  = (const float*)d_in[8];
  const float* input_b  = (const float*)d_in[9];
  const float* fs0_fc_w = (const float*)d_in[10];
  const float* fs0_fc_b = (const float*)d_in[11];
  const float* fs0_glu_w= (const float*)d_in[12];
  const float* fs0_glu_b= (const float*)d_in[13];
  const float* mus      = (const float*)d_in[14];
  const float* isg      = (const float*)d_in[15];
  const float* xproj_w  = (const float*)d_in[16];
  const float* xproj_b  = (const float*)d_in[17];
  const float* seproj_w = (const float*)d_in[18];
  const float* teproj_w = (const float*)d_in[19];
  const float* ln_g     = (const float*)d_in[20];
  const float* ln_b     = (const float*)d_in[21];
  const float* fs_fc_w  = (const float*)d_in[22];
  const float* fs_fc_b  = (const float*)d_in[23];
  const float* fs_glu_w = (const float*)d_in[24];
  const float* fs_glu_b = (const float*)d_in[25];
  const float* glu_w    = (const float*)d_in[26];
  const float* glu_b    = (const float*)d_in[27];
  const float* out_w    = (const float*)d_in[28];
  const float* out_b    = (const float*)d_in[29];

  float* ws    = (float*)d_ws;
  float* hA    = ws;                         // 6,291,456
  float* hB    = hA    + 6291456;            // 6,291,456
  float* W     = hB    + 6291456;            //   786,432
  float* s_part= W     + 786432;             // 2,097,152
  float* hc    = s_part+ 2097152;            // 2,097,152
  float* fwT   = hc    + 2097152;            //   786,432
  float* gwT   = fwT   + 786432;             //   131,072
  float* gluT  = gwT   + 131072;             //   524,288
  float* outT  = gluT  + 524288;             //     6,144
  float* gi    = outT  + 6144;
  float* gj    = gi    + 512;
  float* Ebuf  = gj    + 512;
  float* Fbuf  = Ebuf  + 96;
  float* gtr   = Fbuf  + 288;

  k_prep<<<dim3(2048,10),256,0,stream>>>(fs0_fc_w, fs_fc_w, fs0_glu_w, fs_glu_w,
                                         glu_w, out_w, fwT, gwT, gluT, outT);
  k_input<<<24576,256,0,stream>>>(x, input_w, input_b, hA);
  k_gfs1<<<dim3(8,8,4),256,0,stream>>>(hA, fwT, s_part);
  k_gfs2<<<dim3(16,8),256,0,stream>>>(s_part, fs0_fc_b, gwT, fs0_glu_b, hc, 0);

  float* hcur = hA; float* hnext = hB;
  for (int l=0; l<3; ++l){
    k_smalls<<<1,512,0,stream>>>(sape, tape, trpe, mus, isg, l, gi, gj, Ebuf, Fbuf, gtr);
    k_W<<<1024,256,0,stream>>>(srpe, mask, mus, isg, l, gi, gj, gtr, W);
    k_stpg<<<dim3(96,8),256,0,stream>>>(hcur, W, Ebuf, Fbuf, hnext);
    k_xln<<<dim3(64,96),256,0,stream>>>(hnext, xproj_w, xproj_b, seproj_w, teproj_w,
                                        sape, tape, ln_g, ln_b, l);
    k_gfs1<<<dim3(8,8,4),256,0,stream>>>(hnext, fwT + (size_t)(l+1)*196608, s_part);
    k_gfs2<<<dim3(16,8),256,0,stream>>>(s_part, fs_fc_b + l*128, gwT + (size_t)(l+1)*32768,
                                        fs_glu_b + l*256, hc, l+1);
    float* tmp = hcur; hcur = hnext; hnext = tmp;
  }
  k_final<<<dim3(64,8),256,0,stream>>>(hc, gluT, glu_b, outT, out_b, (float*)d_out);
}

// Round 3
// 992.833 us; speedup vs baseline: 1.5227x; 1.5227x over previous
//
#include <hip/hip_runtime.h>
#include <cstddef>

// ---------------------------------------------------------------------------
// STPGCN forward. B=8 T=12 V=512 C=128 d=8 TSZ=3 L=3 P=12
// S[b,t,j,k,i] = E[b,t]*F[b,t,k]*W[j,k,i]; STPGConv via bf16x3 split MFMA.
// ---------------------------------------------------------------------------

#define BB 8
#define TT 12
#define VV 512
#define CC 128

typedef unsigned short ushort_t;
typedef float f32x4 __attribute__((ext_vector_type(4)));
typedef short bf16x8 __attribute__((ext_vector_type(8)));

__device__ __forceinline__ float sigmoidf_(float x){ return 1.0f/(1.0f+expf(-x)); }

__device__ __forceinline__ void split_bf16(float x, ushort_t& hi, ushort_t& lo){
  unsigned u = __float_as_uint(x);
  hi = (ushort_t)(u >> 16);
  float r = x - __uint_as_float(u & 0xFFFF0000u);
  lo = (ushort_t)(__float_as_uint(r) >> 16);
}

__device__ __forceinline__ float gauss8(const float* __restrict__ e,
                                        const float* __restrict__ mu,
                                        const float* __restrict__ sg){
  float a = 0.f;
  #pragma unroll
  for (int dd=0; dd<8; ++dd){
    float df = e[dd]-mu[dd];
    float s  = sg[dd];
    a = fmaf(-0.5f*df*df, s*s, a);
  }
  return a;
}

// ---------------- weight transposes (once per call) ----------------
__global__ __launch_bounds__(256) void k_prep(
    const float* __restrict__ fs0_fc_w, const float* __restrict__ fs_fc_w,
    const float* __restrict__ fs0_glu_w, const float* __restrict__ fs_glu_w,
    const float* __restrict__ glu_w, const float* __restrict__ out_w,
    float* __restrict__ fwT, float* __restrict__ gwT,
    float* __restrict__ gluT, float* __restrict__ outT){
  int job = blockIdx.y;
  int gid = blockIdx.x*256 + threadIdx.x;
  if (job < 4){                       // fw (128, 12*128) -> fwT[t*128+c][o]
    if (gid >= 196608) return;
    const float* src = (job==0) ? fs0_fc_w : fs_fc_w + (size_t)(job-1)*196608;
    float* dst = fwT + (size_t)job*196608;
    int r = gid / 1536, c = gid % 1536;
    dst[(size_t)c*128 + r] = src[gid];
  } else if (job < 8){                // gw (256,128) -> gwT[o][p]
    if (gid >= 32768) return;
    int sl = job-4;
    const float* src = (sl==0) ? fs0_glu_w : fs_glu_w + (size_t)(sl-1)*32768;
    float* dst = gwT + (size_t)sl*32768;
    int r = gid / 128, c = gid % 128;
    dst[(size_t)c*256 + r] = src[gid];
  } else if (job == 8){               // glu_w (1024,512) -> gluT[o][p]
    if (gid >= 524288) return;
    int r = gid / 512, c = gid % 512;
    gluT[(size_t)c*1024 + r] = glu_w[gid];
  } else {                            // out_w (12,512) -> outT[q][r]
    if (gid >= 6144) return;
    int r = gid / 512, c = gid % 512;
    outT[(size_t)c*12 + r] = out_w[gid];
  }
}

// ---------------- input layer: h = x*iw + ib ; also emit hT bf16 hi/lo -------
__global__ __launch_bounds__(256) void k_input(const float* __restrict__ x,
    const float* __restrict__ iw, const float* __restrict__ ib,
    float* __restrict__ hA, ushort_t* __restrict__ hhiT, ushort_t* __restrict__ hloT){
  int bt = blockIdx.x;              // 96
  int v0 = blockIdx.y*64;           // 8 tiles of 64 v
  int c = threadIdx.x >> 1, half = threadIdx.x & 1;
  int vb = v0 + half*32;
  float wc = iw[c], bc = ib[c];
  const float* xp = x + (size_t)bt*VV + vb;
  float hv[32];
  #pragma unroll
  for (int u=0;u<32;++u) hv[u] = fmaf(xp[u], wc, bc);
  // hA [v][c]
  #pragma unroll
  for (int u=0;u<32;++u) hA[((size_t)bt*VV + vb + u)*CC + c] = hv[u];
  // hT [c][v] bf16 hi/lo
  unsigned wh[16], wl[16];
  #pragma unroll
  for (int m=0;m<16;++m){
    ushort_t h0,l0,h1,l1;
    split_bf16(hv[2*m],   h0, l0);
    split_bf16(hv[2*m+1], h1, l1);
    wh[m] = (unsigned)h0 | ((unsigned)h1<<16);
    wl[m] = (unsigned)l0 | ((unsigned)l1<<16);
  }
  ushort_t* hp = hhiT + ((size_t)bt*CC + c)*VV + vb;
  ushort_t* lp = hloT + ((size_t)bt*CC + c)*VV + vb;
  #pragma unroll
  for (int q=0;q<4;++q){
    *(uint4*)(hp + q*8) = make_uint4(wh[q*4],wh[q*4+1],wh[q*4+2],wh[q*4+3]);
    *(uint4*)(lp + q*8) = make_uint4(wl[q*4],wl[q*4+1],wl[q*4+2],wl[q*4+3]);
  }
}

// ---------------- GFS phase 1: s_part[ts][b][o][v] ----------------
__global__ __launch_bounds__(256) void k_gfs1(const float* __restrict__ h,
    const float* __restrict__ fwT, float* __restrict__ s_part){
  int vt = blockIdx.x, b = blockIdx.y, ts = blockIdx.z;   // 16, 8, 4
  int tid = threadIdx.x;
  int v0 = vt*32;
  __shared__ float hT[32][34];
  int vtt = tid & 3, ot = tid >> 2;    // vtt: 4 x 8v ; ot: 64 x 2o
  float acc[2][8];
  #pragma unroll
  for (int a=0;a<2;++a)
    #pragma unroll
    for (int u=0;u<8;++u) acc[a][u] = 0.f;

  for (int tt=0; tt<3; ++tt){
    int t = ts*3 + tt;
    const float* hbase = h + ((size_t)(b*TT+t)*VV)*CC;
    for (int cch=0; cch<4; ++cch){
      int c0 = cch*32;
      __syncthreads();
      { int vv = tid>>3, c4 = tid&7;
        float4 val = *(const float4*)(hbase + (size_t)(v0+vv)*CC + c0 + c4*4);
        hT[c4*4+0][vv]=val.x; hT[c4*4+1][vv]=val.y;
        hT[c4*4+2][vv]=val.z; hT[c4*4+3][vv]=val.w; }
      __syncthreads();
      const float* fwb = fwT + ((size_t)t*128 + c0)*128 + ot*2;
      for (int c=0;c<32;++c){
        float2 wv = *(const float2*)(fwb + (size_t)c*128);
        float hv[8];
        *(float4*)hv     = *(const float4*)&hT[c][vtt*8];
        *(float4*)(hv+4) = *(const float4*)&hT[c][vtt*8+4];
        #pragma unroll
        for (int u=0;u<8;++u){
          acc[0][u] = fmaf(wv.x, hv[u], acc[0][u]);
          acc[1][u] = fmaf(wv.y, hv[u], acc[1][u]);
        }
      }
    }
  }
  float* sp = s_part + (((size_t)ts*BB+b)*128 + ot*2)*VV + v0 + vtt*8;
  #pragma unroll
  for (int a=0;a<2;++a){
    *(float4*)(sp + (size_t)a*VV)     = *(float4*)&acc[a][0];
    *(float4*)(sp + (size_t)a*VV + 4) = *(float4*)&acc[a][4];
  }
}

// ---------------- GFS phase 2: skip -> hc[b][slot*128+o][v] ----------------
__global__ __launch_bounds__(256) void k_gfs2(const float* __restrict__ s_part,
    const float* __restrict__ fb, const float* __restrict__ gwT,
    const float* __restrict__ gb, float* __restrict__ hc, int slot){
  int vt = blockIdx.x, b = blockIdx.y;
  int v0 = vt*32; int tid = threadIdx.x;
  __shared__ float sL[128][36];
  for (int u=0;u<16;++u){
    int lid = u*256 + tid; int o = lid>>5, vv = lid&31;
    float sum = fb[o];
    #pragma unroll
    for (int sp=0;sp<4;++sp)
      sum += s_part[(((size_t)sp*BB+b)*128 + o)*VV + v0 + vv];
    sL[o][vv] = sum;
  }
  __syncthreads();
  int oo = tid & 127, vg = tid >> 7;
  float accL[16], accR[16];
  #pragma unroll
  for (int u=0;u<16;++u){ accL[u]=0.f; accR[u]=0.f; }
  for (int op=0; op<128; ++op){
    float glv = gwT[(size_t)op*256 + oo];
    float grv = gwT[(size_t)op*256 + 128 + oo];
    float sv[16];
    #pragma unroll
    for (int q=0;q<4;++q) *(float4*)(sv+q*4) = *(const float4*)&sL[op][vg*16 + q*4];
    #pragma unroll
    for (int u=0;u<16;++u){ accL[u]=fmaf(glv,sv[u],accL[u]); accR[u]=fmaf(grv,sv[u],accR[u]); }
  }
  float bl = gb[oo], br = gb[128+oo];
  float outv[16];
  #pragma unroll
  for (int u=0;u<16;++u) outv[u] = (accL[u]+bl)*sigmoidf_(accR[u]+br);
  float* dst = hc + ((size_t)b*512 + slot*128 + oo)*VV + v0 + vg*16;
  #pragma unroll
  for (int q=0;q<4;++q) *(float4*)(dst+q*4) = *(float4*)(outv+q*4);
}

// ---------------- per-layer small gaussians ----------------
__global__ void k_smalls(const float* __restrict__ sape, const float* __restrict__ tape,
    const float* __restrict__ trpe, const float* __restrict__ mus,
    const float* __restrict__ isgs, int l,
    float* __restrict__ gi, float* __restrict__ gj,
    float* __restrict__ E, float* __restrict__ F, float* __restrict__ gtr){
  int tid = threadIdx.x;
  const float* mu = mus  + (size_t)l*48;
  const float* sg = isgs + (size_t)l*48;
  if (tid < 512){
    const float* e = sape + (size_t)tid*8;
    gi[tid] = gauss8(e, mu+0,  sg+0);
    gj[tid] = gauss8(e, mu+8,  sg+8);
  }
  if (tid < 96)
    E[tid] = expf(gauss8(tape + (size_t)tid*8, mu+16, sg+16));
  if (tid < 288){
    int k = tid % 3, bt = tid / 3;
    int t = bt % TT, b = bt / TT;
    int s = t + k - 2;
    F[tid] = (s >= 0) ? expf(gauss8(tape + (size_t)(b*TT+s)*8, mu+24, sg+24)) : 0.f;
  }
  if (tid < 3)
    gtr[tid] = gauss8(trpe + (size_t)tid*8, mu+40, sg+40);
}

// ---- W'[k][j][i] bf16 hi/lo = split( mask[j,k,i]*exp(gi+gj+gtr+ge[i,j]) ) ---
__global__ __launch_bounds__(256) void k_W(const float* __restrict__ srpe,
    const float* __restrict__ mask, const float* __restrict__ mus,
    const float* __restrict__ isgs, int l,
    const float* __restrict__ gi, const float* __restrict__ gj,
    const float* __restrict__ gtr,
    ushort_t* __restrict__ Whi, ushort_t* __restrict__ Wlo){
  int it = blockIdx.x, jt = blockIdx.y;   // 32 x 32 tiles of 16x16
  int tid = threadIdx.x;
  int ii = tid & 15, jj = tid >> 4;
  int i = it*16 + ii, j = jt*16 + jj;
  const float* mu = mus  + (size_t)l*48 + 32;
  const float* sg = isgs + (size_t)l*48 + 32;
  float ge = gauss8(srpe + ((size_t)i*VV + j)*8, mu, sg);
  float base = gi[i] + gj[j] + ge;
  float gk[3] = {gtr[0], gtr[1], gtr[2]};
  __shared__ unsigned tile[16][17];
  int arr = tid>>7, rem = tid&127, jr = rem>>3, p = rem&7;
  for (int k=0;k<3;++k){
    float m = mask[(size_t)j*1536 + k*512 + i];
    float val = m * expf(base + gk[k]);
    ushort_t hi, lo; split_bf16(val, hi, lo);
    __syncthreads();
    tile[jj][ii] = (unsigned)hi | ((unsigned)lo<<16);
    __syncthreads();
    unsigned w0 = tile[jr][2*p], w1 = tile[jr][2*p+1];
    unsigned outw = (arr==0) ? ((w0&0xFFFFu) | (w1<<16))
                             : ((w0>>16) | (w1&0xFFFF0000u));
    ushort_t* dst = (arr ? Wlo : Whi) + ((size_t)k*VV + jt*16 + jr)*VV + it*16 + 2*p;
    *(unsigned*)dst = outw;
  }
}

// ---------------- STPGConv via bf16x3 split MFMA -----------------------------
// agg[bt][j][c] = E * sum_k F_k * (W'_k @ h_s) ; 128x128 tile, BK=32, 4 waves
__global__ __launch_bounds__(256) void k_stpg(
    const ushort_t* __restrict__ hhiT, const ushort_t* __restrict__ hloT,
    const ushort_t* __restrict__ Whi,  const ushort_t* __restrict__ Wlo,
    const float* __restrict__ E, const float* __restrict__ F,
    float* __restrict__ agg){
  int bt = blockIdx.x; int b = bt/TT, t = bt - b*TT;
  int j0 = blockIdx.y * 128;
  int tid = threadIdx.x;
  int lane = tid & 63, wid = tid >> 6;
  int jw = (wid>>1)*64, cw = (wid&1)*64;

  __shared__ ushort_t Ahi_s[128*40];   // rows padded to 40 bf16 (80B = 5x16B)
  __shared__ ushort_t Alo_s[128*40];
  __shared__ ushort_t Bhi_s[128*40];
  __shared__ ushort_t Blo_s[128*40];

  f32x4 acc[4][4];
  #pragma unroll
  for (int a=0;a<4;++a)
    #pragma unroll
    for (int u=0;u<4;++u) acc[a][u] = (f32x4){0.f,0.f,0.f,0.f};

  int kmin = (t>=2) ? 0 : (2-t);
  float Fk[3] = {F[bt*3+0], F[bt*3+1], F[bt*3+2]};
  float Eb = E[bt];

  int ro = (lane&15)*40 + (lane>>4)*8;   // frag base within LDS tile

  for (int k=kmin; k<3; ++k){
    int s = t + k - 2;
    const ushort_t* gAhi = Whi  + ((size_t)k*VV + j0)*VV;
    const ushort_t* gAlo = Wlo  + ((size_t)k*VV + j0)*VV;
    const ushort_t* gBhi = hhiT + (size_t)(b*TT+s)*CC*VV;
    const ushort_t* gBlo = hloT + (size_t)(b*TT+s)*CC*VV;
    for (int i0=0; i0<512; i0+=32){
      __syncthreads();
      #pragma unroll
      for (int p=0;p<2;++p){
        int sl = p*256 + tid;
        int r = sl>>2, q = sl&3;
        size_t go = (size_t)r*VV + i0 + q*8;
        int lo_ = r*40 + q*8;
        *(uint4*)&Ahi_s[lo_] = *(const uint4*)(gAhi + go);
        *(uint4*)&Alo_s[lo_] = *(const uint4*)(gAlo + go);
        *(uint4*)&Bhi_s[lo_] = *(const uint4*)(gBhi + go);
        *(uint4*)&Blo_s[lo_] = *(const uint4*)(gBlo + go);
      }
      __syncthreads();
      bf16x8 ah[4], al[4], bh[4], bl[4];
      #pragma unroll
      for (int f=0; f<4; ++f){
        ah[f] = *(const bf16x8*)&Ahi_s[(jw + f*16)*40 + ro];
        al[f] = *(const bf16x8*)&Alo_s[(jw + f*16)*40 + ro];
        bh[f] = *(const bf16x8*)&Bhi_s[(cw + f*16)*40 + ro];
        bl[f] = *(const bf16x8*)&Blo_s[(cw + f*16)*40 + ro];
      }
      #pragma unroll
      for (int jf=0;jf<4;++jf)
        #pragma unroll
        for (int cf=0;cf<4;++cf){
          acc[jf][cf] = __builtin_amdgcn_mfma_f32_16x16x32_bf16(ah[jf], bh[cf], acc[jf][cf],0,0,0);
          acc[jf][cf] = __builtin_amdgcn_mfma_f32_16x16x32_bf16(ah[jf], bl[cf], acc[jf][cf],0,0,0);
          acc[jf][cf] = __builtin_amdgcn_mfma_f32_16x16x32_bf16(al[jf], bh[cf], acc[jf][cf],0,0,0);
        }
    }
    if (k < 2){
      float r = Fk[k]/Fk[k+1];
      #pragma unroll
      for (int jf=0;jf<4;++jf)
        #pragma unroll
        for (int cf=0;cf<4;++cf) acc[jf][cf] *= r;
    }
  }
  float fin = Fk[2]*Eb;
  #pragma unroll
  for (int jf=0;jf<4;++jf){
    #pragma unroll
    for (int cf=0;cf<4;++cf){
      int row = j0 + jw + jf*16 + (lane>>4)*4;
      int col = cw + cf*16 + (lane&15);
      float* dst = agg + ((size_t)bt*VV + row)*CC + col;
      #pragma unroll
      for (int e=0;e<4;++e) dst[(size_t)e*CC] = acc[jf][cf][e]*fin;
    }
  }
}

// ---------------- xproj + SE/TE proj + LayerNorm + GLU (in place) ------------
// also emits hT bf16 hi/lo for the next layer's MFMA
__global__ __launch_bounds__(256) void k_xln(float* __restrict__ hB,
    const float* __restrict__ xw, const float* __restrict__ xb,
    const float* __restrict__ sw, const float* __restrict__ tw,
    const float* __restrict__ sape, const float* __restrict__ tape,
    const float* __restrict__ lng, const float* __restrict__ lnb, int l,
    ushort_t* __restrict__ hhiT, ushort_t* __restrict__ hloT){
  int v0 = blockIdx.x * 8;
  int bt = blockIdx.y;
  int tid = threadIdx.x;                 // p = tid in [0,256)
  __shared__ float aL[8][128];
  __shared__ float se[8][8];
  __shared__ float te[8];
  __shared__ float zL[8][260];
  __shared__ float stat[8][2];
  float* hrow = hB + ((size_t)bt*VV + v0)*CC;
  { int vv = tid>>5, cc4 = tid&31;
    *(float4*)&aL[vv][cc4*4] = *(const float4*)(hrow + (size_t)vv*CC + cc4*4); }
  if (tid < 64) se[tid>>3][tid&7] = sape[(size_t)(v0 + (tid>>3))*8 + (tid&7)];
  if (tid >= 64 && tid < 72) te[tid-64] = tape[(size_t)bt*8 + (tid-64)];
  __syncthreads();

  const float* xwl = xw + (size_t)l*32768;
  const float* swl = sw + (size_t)l*2048;
  const float* twl = tw + (size_t)l*2048;
  float common = xb[l*256 + tid];
  #pragma unroll
  for (int dd=0; dd<8; ++dd) common = fmaf(te[dd], twl[dd*256+tid], common);
  float z[8];
  #pragma unroll
  for (int vv=0; vv<8; ++vv){
    float sacc = common;
    #pragma unroll
    for (int dd=0; dd<8; ++dd) sacc = fmaf(se[vv][dd], swl[dd*256+tid], sacc);
    z[vv] = sacc;
  }
  for (int c4=0; c4<32; ++c4){
    float x0 = xwl[(c4*4+0)*256 + tid];
    float x1 = xwl[(c4*4+1)*256 + tid];
    float x2 = xwl[(c4*4+2)*256 + tid];
    float x3 = xwl[(c4*4+3)*256 + tid];
    #pragma unroll
    for (int vv=0; vv<8; ++vv){
      float4 a4 = *(const float4*)&aL[vv][c4*4];
      z[vv] = fmaf(a4.x,x0, fmaf(a4.y,x1, fmaf(a4.z,x2, fmaf(a4.w,x3, z[vv]))));
    }
  }
  #pragma unroll
  for (int vv=0; vv<8; ++vv) zL[vv][tid] = z[vv];
  __syncthreads();
  { int vv = tid>>5, sub = tid&31;
    float s1=0.f, s2=0.f;
    #pragma unroll
    for (int u=0; u<8; ++u){ float val = zL[vv][sub + u*32]; s1 += val; s2 = fmaf(val,val,s2); }
    #pragma unroll
    for (int off=16; off>=1; off>>=1){
      s1 += __shfl_down(s1, off, 32);
      s2 += __shfl_down(s2, off, 32);
    }
    if (sub==0){
      float mn = s1*(1.f/256.f);
      float var = s2*(1.f/256.f) - mn*mn;
      stat[vv][0] = mn;
      stat[vv][1] = 1.f/sqrtf(var + 1e-5f);
    }
  }
  __syncthreads();
  { int vv = tid>>5, sub = tid&31;
    float mn = stat[vv][0], rs = stat[vv][1];
    float4 zl = *(const float4*)&zL[vv][sub*4];
    float4 zr = *(const float4*)&zL[vv][sub*4+128];
    float zlv[4] = {zl.x,zl.y,zl.z,zl.w};
    float zrv[4] = {zr.x,zr.y,zr.z,zr.w};
    float ov[4];
    #pragma unroll
    for (int u=0; u<4; ++u){
      int c = sub*4 + u;
      float nl = (zlv[u]-mn)*rs*lng[l*256 + c]       + lnb[l*256 + c];
      float nr = (zrv[u]-mn)*rs*lng[l*256 + 128 + c] + lnb[l*256 + 128 + c];
      ov[u] = nl * sigmoidf_(nr);
    }
    *(float4*)(hrow + (size_t)vv*CC + sub*4) = *(float4*)ov;
    // stage for transposed bf16 emit
    zL[vv][sub*4+0]=ov[0]; zL[vv][sub*4+1]=ov[1]; zL[vv][sub*4+2]=ov[2]; zL[vv][sub*4+3]=ov[3];
  }
  __syncthreads();
  { int cc = tid & 127, sel = tid >> 7;
    float g[8];
    #pragma unroll
    for (int u=0;u<8;++u) g[u] = zL[u][cc];
    unsigned w[4];
    #pragma unroll
    for (int m=0;m<4;++m){
      ushort_t h0,l0,h1,l1;
      split_bf16(g[2*m],   h0, l0);
      split_bf16(g[2*m+1], h1, l1);
      w[m] = sel ? ((unsigned)l0 | ((unsigned)l1<<16))
                 : ((unsigned)h0 | ((unsigned)h1<<16));
    }
    ushort_t* dst = (sel ? hloT : hhiT) + ((size_t)bt*CC + cc)*VV + v0;
    *(uint4*)dst = make_uint4(w[0],w[1],w[2],w[3]);
  }
}

// ---------------- final GLU + out ----------------
__global__ __launch_bounds__(256) void k_final(const float* __restrict__ hc,
    const float* __restrict__ gluT, const float* __restrict__ glub,
    const float* __restrict__ outT, const float* __restrict__ outb,
    float* __restrict__ out){
  int b = blockIdx.y; int v0 = blockIdx.x * 8;
  int tid = threadIdx.x;
  __shared__ float hcl[512][8];
  __shared__ float gl[512][9];
  for (int u=0; u<16; ++u){
    int lid = u*256 + tid; int o = lid>>3, vv = lid&7;
    hcl[o][vv] = hc[((size_t)b*512 + o)*VV + v0 + vv];
  }
  __syncthreads();
  float aL0[8], aR0[8], aL1[8], aR1[8];
  #pragma unroll
  for (int u=0;u<8;++u){ aL0[u]=0.f; aR0[u]=0.f; aL1[u]=0.f; aR1[u]=0.f; }
  for (int o=0; o<512; ++o){
    const float* grow = gluT + (size_t)o*1024;
    float g0 = grow[tid], g1 = grow[tid+256], g2 = grow[tid+512], g3 = grow[tid+768];
    float hv[8];
    *(float4*)hv     = *(const float4*)&hcl[o][0];
    *(float4*)(hv+4) = *(const float4*)&hcl[o][4];
    #pragma unroll
    for (int u=0;u<8;++u){
      aL0[u]=fmaf(g0,hv[u],aL0[u]); aL1[u]=fmaf(g1,hv[u],aL1[u]);
      aR0[u]=fmaf(g2,hv[u],aR0[u]); aR1[u]=fmaf(g3,hv[u],aR1[u]);
    }
  }
  float bL0 = glub[tid], bL1 = glub[tid+256], bR0 = glub[tid+512], bR1 = glub[tid+768];
  #pragma unroll
  for (int u=0;u<8;++u){
    gl[tid][u]     = (aL0[u]+bL0)*sigmoidf_(aR0[u]+bR0);
    gl[tid+256][u] = (aL1[u]+bL1)*sigmoidf_(aR1[u]+bR1);
  }
  __syncthreads();
  if (tid < 96){
    int r = tid>>3, vv = tid&7;
    float acc = outb[r];
    for (int q=0; q<512; ++q) acc = fmaf(outT[(size_t)q*12 + r], gl[q][vv], acc);
    out[(size_t)b*6144 + r*512 + v0 + vv] = acc;
  }
}

// ---------------------------------------------------------------------------
extern "C" void kernel_launch(void* const* d_in, const int* in_sizes, int n_in,
                              void* d_out, int out_size, void* d_ws, size_t ws_size,
                              hipStream_t stream){
  const float* x        = (const float*)d_in[0];
  const float* sape     = (const float*)d_in[1];
  const float* tape     = (const float*)d_in[2];
  const float* srpe     = (const float*)d_in[3];
  const float* trpe     = (const float*)d_in[4];
  const float* mask     = (const float*)d_in[7];
  const float* input_w  = (const float*)d_in[8];
  const float* input_b  = (const float*)d_in[9];
  const float* fs0_fc_w = (const float*)d_in[10];
  const float* fs0_fc_b = (const float*)d_in[11];
  const float* fs0_glu_w= (const float*)d_in[12];
  const float* fs0_glu_b= (const float*)d_in[13];
  const float* mus      = (const float*)d_in[14];
  const float* isg      = (const float*)d_in[15];
  const float* xproj_w  = (const float*)d_in[16];
  const float* xproj_b  = (const float*)d_in[17];
  const float* seproj_w = (const float*)d_in[18];
  const float* teproj_w = (const float*)d_in[19];
  const float* ln_g     = (const float*)d_in[20];
  const float* ln_b     = (const float*)d_in[21];
  const float* fs_fc_w  = (const float*)d_in[22];
  const float* fs_fc_b  = (const float*)d_in[23];
  const float* fs_glu_w = (const float*)d_in[24];
  const float* fs_glu_b = (const float*)d_in[25];
  const float* glu_w    = (const float*)d_in[26];
  const float* glu_b    = (const float*)d_in[27];
  const float* out_w    = (const float*)d_in[28];
  const float* out_b    = (const float*)d_in[29];

  float* ws    = (float*)d_ws;
  float* hA    = ws;                          // 6,291,456
  float* hc    = hA    + 6291456;             // 2,097,152
  float* s_part= hc    + 2097152;             // 2,097,152
  float* fwT   = s_part+ 2097152;             //   786,432
  float* gwT   = fwT   + 786432;              //   131,072
  float* gluT  = gwT   + 131072;              //   524,288
  float* outT  = gluT  + 524288;              //     6,144
  float* gi    = outT  + 6144;                //       512
  float* gj    = gi    + 512;                 //       512
  float* Ebuf  = gj    + 512;                 //        96
  float* Fbuf  = Ebuf  + 96;                  //       288
  float* gtr   = Fbuf  + 288;                 //        16 (pad)
  ushort_t* hhiT = (ushort_t*)(gtr + 16);     // 6,291,456 ushorts
  ushort_t* hloT = hhiT + 6291456;            // 6,291,456 ushorts
  ushort_t* Whi  = hloT + 6291456;            //   786,432 ushorts
  ushort_t* Wlo  = Whi  + 786432;             //   786,432 ushorts

  k_prep<<<dim3(2048,10),256,0,stream>>>(fs0_fc_w, fs_fc_w, fs0_glu_w, fs_glu_w,
                                         glu_w, out_w, fwT, gwT, gluT, outT);
  k_input<<<dim3(96,8),256,0,stream>>>(x, input_w, input_b, hA, hhiT, hloT);
  k_gfs1<<<dim3(16,8,4),256,0,stream>>>(hA, fwT, s_part);
  k_gfs2<<<dim3(16,8),256,0,stream>>>(s_part, fs0_fc_b, gwT, fs0_glu_b, hc, 0);

  for (int l=0; l<3; ++l){
    k_smalls<<<1,512,0,stream>>>(sape, tape, trpe, mus, isg, l, gi, gj, Ebuf, Fbuf, gtr);
    k_W<<<dim3(32,32),256,0,stream>>>(srpe, mask, mus, isg, l, gi, gj, gtr, Whi, Wlo);
    k_stpg<<<dim3(96,4),256,0,stream>>>(hhiT, hloT, Whi, Wlo, Ebuf, Fbuf, hA);
    k_xln<<<dim3(64,96),256,0,stream>>>(hA, xproj_w, xproj_b, seproj_w, teproj_w,
                                        sape, tape, ln_g, ln_b, l, hhiT, hloT);
    k_gfs1<<<dim3(16,8,4),256,0,stream>>>(hA, fwT + (size_t)(l+1)*196608, s_part);
    k_gfs2<<<dim3(16,8),256,0,stream>>>(s_part, fs_fc_b + l*128, gwT + (size_t)(l+1)*32768,
                                        fs_glu_b + l*256, hc, l+1);
  }
  k_final<<<dim3(64,8),256,0,stream>>>(hc, gluT, glu_b, outT, out_b, (float*)d_out);
}

// Round 6
// 877.557 us; speedup vs baseline: 1.7228x; 1.1314x over previous
//
#include <hip/hip_runtime.h>
#include <cstddef>

// ---------------------------------------------------------------------------
// STPGCN forward. B=8 T=12 V=512 C=128 d=8 TSZ=3 L=3 P=12
// S[b,t,j,k,i] = E[b,t]*F[b,t,k]*W[j,k,i]; STPGConv + xproj via bf16x3 MFMA.
// ---------------------------------------------------------------------------

#define BB 8
#define TT 12
#define VV 512
#define CC 128

typedef unsigned short ushort_t;
typedef float f32x4 __attribute__((ext_vector_type(4)));
typedef short bf16x8 __attribute__((ext_vector_type(8)));

__device__ __forceinline__ float sigmoidf_(float x){ return 1.0f/(1.0f+expf(-x)); }

__device__ __forceinline__ void split_bf16(float x, ushort_t& hi, ushort_t& lo){
  unsigned u = __float_as_uint(x);
  hi = (ushort_t)(u >> 16);
  float r = x - __uint_as_float(u & 0xFFFF0000u);
  lo = (ushort_t)(__float_as_uint(r) >> 16);
}

__device__ __forceinline__ float gauss8(const float* __restrict__ e,
                                        const float* __restrict__ mu,
                                        const float* __restrict__ sg){
  float a = 0.f;
  #pragma unroll
  for (int dd=0; dd<8; ++dd){
    float df = e[dd]-mu[dd];
    float s  = sg[dd];
    a = fmaf(-0.5f*df*df, s*s, a);
  }
  return a;
}

// ---------------- weight transposes / bf16 prep (once per call) --------------
__global__ __launch_bounds__(256) void k_prep(
    const float* __restrict__ fs0_fc_w, const float* __restrict__ fs_fc_w,
    const float* __restrict__ fs0_glu_w, const float* __restrict__ fs_glu_w,
    const float* __restrict__ glu_w, const float* __restrict__ out_w,
    const float* __restrict__ xw, const float* __restrict__ sw,
    const float* __restrict__ tw, const float* __restrict__ xb2,
    float* __restrict__ fwT, float* __restrict__ gwT,
    float* __restrict__ gluT, float* __restrict__ outT,
    ushort_t* __restrict__ xcat_hi, ushort_t* __restrict__ xcat_lo){
  int job = blockIdx.y;
  int gid = blockIdx.x*256 + threadIdx.x;
  if (job < 4){                       // fw (128, 12*128) -> fwT[t*128+c][o]
    if (gid >= 196608) return;
    const float* src = (job==0) ? fs0_fc_w : fs_fc_w + (size_t)(job-1)*196608;
    float* dst = fwT + (size_t)job*196608;
    int r = gid / 1536, c = gid % 1536;
    dst[(size_t)c*128 + r] = src[gid];
  } else if (job < 8){                // gw (256,128) -> gwT[o][p]
    if (gid >= 32768) return;
    int sl = job-4;
    const float* src = (sl==0) ? fs0_glu_w : fs_glu_w + (size_t)(sl-1)*32768;
    float* dst = gwT + (size_t)sl*32768;
    int r = gid / 128, c = gid % 128;
    dst[(size_t)c*256 + r] = src[gid];
  } else if (job == 8){               // glu_w (1024,512) -> gluT[o][p]
    if (gid >= 524288) return;
    int r = gid / 512, c = gid % 512;
    gluT[(size_t)c*1024 + r] = glu_w[gid];
  } else if (job == 9){               // out_w (12,512) -> outT[q][r]
    if (gid >= 6144) return;
    int r = gid / 512, c = gid % 512;
    outT[(size_t)c*12 + r] = out_w[gid];
  } else {                            // xcat[l][col][k=160] bf16 hi/lo
    if (gid >= 122880) return;
    int ll  = gid / 40960;
    int rem = gid - ll*40960;
    int col = rem / 160;
    int k   = rem - col*160;
    float val;
    if (k < 128)       val = xw[(size_t)ll*32768 + (size_t)k*256 + col];
    else if (k < 136)  val = sw[(size_t)ll*2048 + (size_t)(k-128)*256 + col];
    else if (k < 144)  val = tw[(size_t)ll*2048 + (size_t)(k-136)*256 + col];
    else if (k == 144) val = xb2[ll*256 + col];
    else               val = 0.f;
    ushort_t hi, lo; split_bf16(val, hi, lo);
    xcat_hi[gid] = hi;
    xcat_lo[gid] = lo;
  }
}

// ---------------- input layer: h = x*iw + ib ; also emit hT bf16 hi/lo -------
__global__ __launch_bounds__(256) void k_input(const float* __restrict__ x,
    const float* __restrict__ iw, const float* __restrict__ ib,
    float* __restrict__ hA, ushort_t* __restrict__ hhiT, ushort_t* __restrict__ hloT){
  int bt = blockIdx.x;              // 96
  int v0 = blockIdx.y*64;           // 8 tiles of 64 v
  int c = threadIdx.x >> 1, half = threadIdx.x & 1;
  int vb = v0 + half*32;
  float wc = iw[c], bc = ib[c];
  const float* xp = x + (size_t)bt*VV + vb;
  float hv[32];
  #pragma unroll
  for (int u=0;u<32;++u) hv[u] = fmaf(xp[u], wc, bc);
  // hA [v][c]
  #pragma unroll
  for (int u=0;u<32;++u) hA[((size_t)bt*VV + vb + u)*CC + c] = hv[u];
  // hT [c][v] bf16 hi/lo
  unsigned wh[16], wl[16];
  #pragma unroll
  for (int m=0;m<16;++m){
    ushort_t h0,l0,h1,l1;
    split_bf16(hv[2*m],   h0, l0);
    split_bf16(hv[2*m+1], h1, l1);
    wh[m] = (unsigned)h0 | ((unsigned)h1<<16);
    wl[m] = (unsigned)l0 | ((unsigned)l1<<16);
  }
  ushort_t* hp = hhiT + ((size_t)bt*CC + c)*VV + vb;
  ushort_t* lp = hloT + ((size_t)bt*CC + c)*VV + vb;
  #pragma unroll
  for (int q=0;q<4;++q){
    *(uint4*)(hp + q*8) = make_uint4(wh[q*4],wh[q*4+1],wh[q*4+2],wh[q*4+3]);
    *(uint4*)(lp + q*8) = make_uint4(wl[q*4],wl[q*4+1],wl[q*4+2],wl[q*4+3]);
  }
}

// ---------------- GFS phase 1: s_part[ts][b][o][v] ----------------
__global__ __launch_bounds__(256) void k_gfs1(const float* __restrict__ h,
    const float* __restrict__ fwT, float* __restrict__ s_part){
  int vt = blockIdx.x, b = blockIdx.y, ts = blockIdx.z;   // 16, 8, 4
  int tid = threadIdx.x;
  int v0 = vt*32;
  __shared__ float hT[32][34];
  int vtt = tid & 3, ot = tid >> 2;    // vtt: 4 x 8v ; ot: 64 x 2o
  float acc[2][8];
  #pragma unroll
  for (int a=0;a<2;++a)
    #pragma unroll
    for (int u=0;u<8;++u) acc[a][u] = 0.f;

  for (int tt=0; tt<3; ++tt){
    int t = ts*3 + tt;
    const float* hbase = h + ((size_t)(b*TT+t)*VV)*CC;
    for (int cch=0; cch<4; ++cch){
      int c0 = cch*32;
      __syncthreads();
      { int vv = tid>>3, c4 = tid&7;
        float4 val = *(const float4*)(hbase + (size_t)(v0+vv)*CC + c0 + c4*4);
        hT[c4*4+0][vv]=val.x; hT[c4*4+1][vv]=val.y;
        hT[c4*4+2][vv]=val.z; hT[c4*4+3][vv]=val.w; }
      __syncthreads();
      const float* fwb = fwT + ((size_t)t*128 + c0)*128 + ot*2;
      for (int c=0;c<32;++c){
        float2 wv = *(const float2*)(fwb + (size_t)c*128);
        float hv[8];
        *(float4*)hv     = *(const float4*)&hT[c][vtt*8];
        *(float4*)(hv+4) = *(const float4*)&hT[c][vtt*8+4];
        #pragma unroll
        for (int u=0;u<8;++u){
          acc[0][u] = fmaf(wv.x, hv[u], acc[0][u]);
          acc[1][u] = fmaf(wv.y, hv[u], acc[1][u]);
        }
      }
    }
  }
  float* sp = s_part + (((size_t)ts*BB+b)*128 + ot*2)*VV + v0 + vtt*8;
  #pragma unroll
  for (int a=0;a<2;++a){
    *(float4*)(sp + (size_t)a*VV)     = *(float4*)&acc[a][0];
    *(float4*)(sp + (size_t)a*VV + 4) = *(float4*)&acc[a][4];
  }
}

// ---------------- GFS phase 2: skip -> hc[b][slot*128+o][v] ----------------
__global__ __launch_bounds__(256) void k_gfs2(const float* __restrict__ s_part,
    const float* __restrict__ fb, const float* __restrict__ gwT,
    const float* __restrict__ gb, float* __restrict__ hc, int slot){
  int vt = blockIdx.x, b = blockIdx.y;
  int v0 = vt*32; int tid = threadIdx.x;
  __shared__ float sL[128][36];
  for (int u=0;u<16;++u){
    int lid = u*256 + tid; int o = lid>>5, vv = lid&31;
    float sum = fb[o];
    #pragma unroll
    for (int sp=0;sp<4;++sp)
      sum += s_part[(((size_t)sp*BB+b)*128 + o)*VV + v0 + vv];
    sL[o][vv] = sum;
  }
  __syncthreads();
  int oo = tid & 127, vg = tid >> 7;
  float accL[16], accR[16];
  #pragma unroll
  for (int u=0;u<16;++u){ accL[u]=0.f; accR[u]=0.f; }
  for (int op=0; op<128; ++op){
    float glv = gwT[(size_t)op*256 + oo];
    float grv = gwT[(size_t)op*256 + 128 + oo];
    float sv[16];
    #pragma unroll
    for (int q=0;q<4;++q) *(float4*)(sv+q*4) = *(const float4*)&sL[op][vg*16 + q*4];
    #pragma unroll
    for (int u=0;u<16;++u){ accL[u]=fmaf(glv,sv[u],accL[u]); accR[u]=fmaf(grv,sv[u],accR[u]); }
  }
  float bl = gb[oo], br = gb[128+oo];
  float outv[16];
  #pragma unroll
  for (int u=0;u<16;++u) outv[u] = (accL[u]+bl)*sigmoidf_(accR[u]+br);
  float* dst = hc + ((size_t)b*512 + slot*128 + oo)*VV + v0 + vg*16;
  #pragma unroll
  for (int q=0;q<4;++q) *(float4*)(dst+q*4) = *(float4*)(outv+q*4);
}

// ---------------- per-layer small gaussians ----------------
__global__ void k_smalls(const float* __restrict__ sape, const float* __restrict__ tape,
    const float* __restrict__ trpe, const float* __restrict__ mus,
    const float* __restrict__ isgs, int l,
    float* __restrict__ gi, float* __restrict__ gj,
    float* __restrict__ E, float* __restrict__ F, float* __restrict__ gtr){
  int tid = threadIdx.x;
  const float* mu = mus  + (size_t)l*48;
  const float* sg = isgs + (size_t)l*48;
  if (tid < 512){
    const float* e = sape + (size_t)tid*8;
    gi[tid] = gauss8(e, mu+0,  sg+0);
    gj[tid] = gauss8(e, mu+8,  sg+8);
  }
  if (tid < 96)
    E[tid] = expf(gauss8(tape + (size_t)tid*8, mu+16, sg+16));
  if (tid < 288){
    int k = tid % 3, bt = tid / 3;
    int t = bt % TT, b = bt / TT;
    int s = t + k - 2;
    F[tid] = (s >= 0) ? expf(gauss8(tape + (size_t)(b*TT+s)*8, mu+24, sg+24)) : 0.f;
  }
  if (tid < 3)
    gtr[tid] = gauss8(trpe + (size_t)tid*8, mu+40, sg+40);
}

// ---- W'[k][j][i] bf16 hi/lo = split( mask[j,k,i]*exp(gi+gj+gtr+ge[i,j]) ) ---
__global__ __launch_bounds__(256) void k_W(const float* __restrict__ srpe,
    const float* __restrict__ mask, const float* __restrict__ mus,
    const float* __restrict__ isgs, int l,
    const float* __restrict__ gi, const float* __restrict__ gj,
    const float* __restrict__ gtr,
    ushort_t* __restrict__ Whi, ushort_t* __restrict__ Wlo){
  int it = blockIdx.x, jt = blockIdx.y;   // 32 x 32 tiles of 16x16
  int tid = threadIdx.x;
  int ii = tid & 15, jj = tid >> 4;
  int i = it*16 + ii, j = jt*16 + jj;
  const float* mu = mus  + (size_t)l*48 + 32;
  const float* sg = isgs + (size_t)l*48 + 32;
  float ge = gauss8(srpe + ((size_t)i*VV + j)*8, mu, sg);
  float base = gi[i] + gj[j] + ge;
  float gk[3] = {gtr[0], gtr[1], gtr[2]};
  __shared__ unsigned tile[16][17];
  int arr = tid>>7, rem = tid&127, jr = rem>>3, p = rem&7;
  for (int k=0;k<3;++k){
    float m = mask[(size_t)j*1536 + k*512 + i];
    float val = m * expf(base + gk[k]);
    ushort_t hi, lo; split_bf16(val, hi, lo);
    __syncthreads();
    tile[jj][ii] = (unsigned)hi | ((unsigned)lo<<16);
    __syncthreads();
    unsigned w0 = tile[jr][2*p], w1 = tile[jr][2*p+1];
    unsigned outw = (arr==0) ? ((w0&0xFFFFu) | (w1<<16))
                             : ((w0>>16) | (w1&0xFFFF0000u));
    ushort_t* dst = (arr ? Wlo : Whi) + ((size_t)k*VV + jt*16 + jr)*VV + it*16 + 2*p;
    *(unsigned*)dst = outw;
  }
}

// ---------------- STPGConv via bf16x3 split MFMA -----------------------------
// agg[bt][j][c] = E * sum_k F_k * (W'_k @ h_s) ; 128x128 tile, BK=32, 4 waves
__global__ __launch_bounds__(256) void k_stpg(
    const ushort_t* __restrict__ hhiT, const ushort_t* __restrict__ hloT,
    const ushort_t* __restrict__ Whi,  const ushort_t* __restrict__ Wlo,
    const float* __restrict__ E, const float* __restrict__ F,
    float* __restrict__ agg){
  int bt = blockIdx.x; int b = bt/TT, t = bt - b*TT;
  int j0 = blockIdx.y * 128;
  int tid = threadIdx.x;
  int lane = tid & 63, wid = tid >> 6;
  int jw = (wid>>1)*64, cw = (wid&1)*64;

  __shared__ ushort_t Ahi_s[128*40];   // rows padded to 40 bf16 (80B = 5x16B)
  __shared__ ushort_t Alo_s[128*40];
  __shared__ ushort_t Bhi_s[128*40];
  __shared__ ushort_t Blo_s[128*40];

  f32x4 acc[4][4];
  #pragma unroll
  for (int a=0;a<4;++a)
    #pragma unroll
    for (int u=0;u<4;++u) acc[a][u] = (f32x4){0.f,0.f,0.f,0.f};

  int kmin = (t>=2) ? 0 : (2-t);
  float Fk[3] = {F[bt*3+0], F[bt*3+1], F[bt*3+2]};
  float Eb = E[bt];

  int ro = (lane&15)*40 + (lane>>4)*8;   // frag base within LDS tile

  for (int k=kmin; k<3; ++k){
    int s = t + k - 2;
    const ushort_t* gAhi = Whi  + ((size_t)k*VV + j0)*VV;
    const ushort_t* gAlo = Wlo  + ((size_t)k*VV + j0)*VV;
    const ushort_t* gBhi = hhiT + (size_t)(b*TT+s)*CC*VV;
    const ushort_t* gBlo = hloT + (size_t)(b*TT+s)*CC*VV;
    for (int i0=0; i0<512; i0+=32){
      __syncthreads();
      #pragma unroll
      for (int p=0;p<2;++p){
        int sl = p*256 + tid;
        int r = sl>>2, q = sl&3;
        size_t go = (size_t)r*VV + i0 + q*8;
        int lo_ = r*40 + q*8;
        *(uint4*)&Ahi_s[lo_] = *(const uint4*)(gAhi + go);
        *(uint4*)&Alo_s[lo_] = *(const uint4*)(gAlo + go);
        *(uint4*)&Bhi_s[lo_] = *(const uint4*)(gBhi + go);
        *(uint4*)&Blo_s[lo_] = *(const uint4*)(gBlo + go);
      }
      __syncthreads();
      bf16x8 ah[4], al[4], bh[4], bl[4];
      #pragma unroll
      for (int f=0; f<4; ++f){
        ah[f] = *(const bf16x8*)&Ahi_s[(jw + f*16)*40 + ro];
        al[f] = *(const bf16x8*)&Alo_s[(jw + f*16)*40 + ro];
        bh[f] = *(const bf16x8*)&Bhi_s[(cw + f*16)*40 + ro];
        bl[f] = *(const bf16x8*)&Blo_s[(cw + f*16)*40 + ro];
      }
      #pragma unroll
      for (int jf=0;jf<4;++jf)
        #pragma unroll
        for (int cf=0;cf<4;++cf){
          acc[jf][cf] = __builtin_amdgcn_mfma_f32_16x16x32_bf16(ah[jf], bh[cf], acc[jf][cf],0,0,0);
          acc[jf][cf] = __builtin_amdgcn_mfma_f32_16x16x32_bf16(ah[jf], bl[cf], acc[jf][cf],0,0,0);
          acc[jf][cf] = __builtin_amdgcn_mfma_f32_16x16x32_bf16(al[jf], bh[cf], acc[jf][cf],0,0,0);
        }
    }
    if (k < 2){
      float r = Fk[k]/Fk[k+1];
      #pragma unroll
      for (int jf=0;jf<4;++jf)
        #pragma unroll
        for (int cf=0;cf<4;++cf) acc[jf][cf] *= r;
    }
  }
  float fin = Fk[2]*Eb;
  #pragma unroll
  for (int jf=0;jf<4;++jf){
    #pragma unroll
    for (int cf=0;cf<4;++cf){
      int row = j0 + jw + jf*16 + (lane>>4)*4;
      int col = cw + cf*16 + (lane&15);
      float* dst = agg + ((size_t)bt*VV + row)*CC + col;
      #pragma unroll
      for (int e=0;e<4;++e) dst[(size_t)e*CC] = acc[jf][cf][e]*fin;
    }
  }
}

// ---------------- xproj+SE+TE+bias (MFMA, K=160) + LayerNorm + GLU -----------
// acc layout per wave: rows = w*32 + m*16 + (lane>>4)*4 + e ; cols = n*16 + (lane&15)
__global__ __launch_bounds__(256,2) void k_xln2(
    float* __restrict__ hA,                       // in: agg f32; out: h f32 (in place)
    const ushort_t* __restrict__ xcat_hi, const ushort_t* __restrict__ xcat_lo,
    const float* __restrict__ sape, const float* __restrict__ tape,
    const float* __restrict__ lng, const float* __restrict__ lnb, int l,
    ushort_t* __restrict__ hhiT, ushort_t* __restrict__ hloT){
  int vt = blockIdx.x, bt = blockIdx.y;
  int v0 = vt*128;
  int tid = threadIdx.x;
  int lane = tid & 63, w = tid >> 6;
  int l15 = lane & 15, l4 = lane >> 4;
  int ko = l4*8;

  __shared__ float sef[128][8];
  __shared__ float tef[8];
  __shared__ float lnwS[256], lnbS[256];
  { int r2 = tid>>1, hh = tid&1;
    *(float4*)&sef[r2][hh*4] = *(const float4*)(sape + (size_t)(v0+r2)*8 + hh*4); }
  if (tid < 8) tef[tid] = tape[(size_t)bt*8 + tid];
  lnwS[tid] = lng[l*256 + tid];
  lnbS[tid] = lnb[l*256 + tid];
  __syncthreads();

  f32x4 acc[2][16];
  #pragma unroll
  for (int m=0;m<2;++m)
    #pragma unroll
    for (int n=0;n<16;++n) acc[m][n] = (f32x4){0.f,0.f,0.f,0.f};

  const ushort_t* bhb = xcat_hi + (size_t)l*40960;
  const ushort_t* blb = xcat_lo + (size_t)l*40960;

  #pragma unroll
  for (int ks=0; ks<5; ++ks){
    bf16x8 a_h[2], a_l[2];
    #pragma unroll
    for (int m=0;m<2;++m){
      int lrow = w*32 + m*16 + l15;
      float av[8];
      if (ks < 4){
        const float* ap = hA + ((size_t)bt*VV + v0 + lrow)*CC + ks*32 + ko;
        *(float4*)av     = *(const float4*)ap;
        *(float4*)(av+4) = *(const float4*)(ap+4);
      } else {
        #pragma unroll
        for (int u=0;u<8;++u) av[u] = 0.f;
        if (l4==0){
          #pragma unroll
          for (int u=0;u<8;++u) av[u] = sef[lrow][u];
        } else if (l4==1){
          #pragma unroll
          for (int u=0;u<8;++u) av[u] = tef[u];
        } else if (l4==2){
          av[0] = 1.f;
        }
      }
      #pragma unroll
      for (int u=0;u<8;++u){
        ushort_t hi, lo; split_bf16(av[u], hi, lo);
        a_h[m][u] = (short)hi; a_l[m][u] = (short)lo;
      }
    }
    #pragma unroll
    for (int n=0;n<16;++n){
      size_t boff = (size_t)(n*16 + l15)*160 + ks*32 + ko;
      bf16x8 b_h = *(const bf16x8*)(bhb + boff);
      bf16x8 b_l = *(const bf16x8*)(blb + boff);
      #pragma unroll
      for (int m=0;m<2;++m){
        acc[m][n] = __builtin_amdgcn_mfma_f32_16x16x32_bf16(a_h[m], b_h, acc[m][n],0,0,0);
        acc[m][n] = __builtin_amdgcn_mfma_f32_16x16x32_bf16(a_h[m], b_l, acc[m][n],0,0,0);
        acc[m][n] = __builtin_amdgcn_mfma_f32_16x16x32_bf16(a_l[m], b_h, acc[m][n],0,0,0);
      }
    }
  }

  // LayerNorm stats: row's 256 cols live across this 16-lane group
  float mn[2][4], rs[2][4];
  #pragma unroll
  for (int m=0;m<2;++m){
    #pragma unroll
    for (int e=0;e<4;++e){
      float s1=0.f, s2=0.f;
      #pragma unroll
      for (int n=0;n<16;++n){ float v = acc[m][n][e]; s1 += v; s2 = fmaf(v,v,s2); }
      #pragma unroll
      for (int off=8; off>=1; off>>=1){
        s1 += __shfl_xor(s1, off, 64);
        s2 += __shfl_xor(s2, off, 64);
      }
      float mu = s1*(1.f/256.f);
      mn[m][e] = mu;
      rs[m][e] = 1.f/sqrtf(s2*(1.f/256.f) - mu*mu + 1e-5f);
    }
  }

  // GLU + writes: h f32 in place, hT bf16 hi/lo
  float* hbase = hA + ((size_t)bt*VV)*CC;
  #pragma unroll
  for (int m=0;m<2;++m){
    #pragma unroll
    for (int n=0;n<8;++n){
      int cL = n*16 + l15, cR = cL + 128;
      float gL = lnwS[cL], bL = lnbS[cL];
      float gR = lnwS[cR], bR = lnbS[cR];
      ushort_t hi4[4], lo4[4];
      #pragma unroll
      for (int e=0;e<4;++e){
        float nl = (acc[m][n][e]   - mn[m][e])*rs[m][e]*gL + bL;
        float nr = (acc[m][n+8][e] - mn[m][e])*rs[m][e]*gR + bR;
        float hv = nl * sigmoidf_(nr);
        int v = v0 + w*32 + m*16 + l4*4 + e;
        hbase[(size_t)v*CC + cL] = hv;
        split_bf16(hv, hi4[e], lo4[e]);
      }
      int vbase = v0 + w*32 + m*16 + l4*4;
      ushort_t* hp = hhiT + ((size_t)bt*CC + cL)*VV + vbase;
      ushort_t* lp = hloT + ((size_t)bt*CC + cL)*VV + vbase;
      *(uint2*)hp = make_uint2((unsigned)hi4[0] | ((unsigned)hi4[1]<<16),
                               (unsigned)hi4[2] | ((unsigned)hi4[3]<<16));
      *(uint2*)lp = make_uint2((unsigned)lo4[0] | ((unsigned)lo4[1]<<16),
                               (unsigned)lo4[2] | ((unsigned)lo4[3]<<16));
    }
  }
}

// ---------------- final GLU + out ----------------
__global__ __launch_bounds__(256) void k_final(const float* __restrict__ hc,
    const float* __restrict__ gluT, const float* __restrict__ glub,
    const float* __restrict__ outT, const float* __restrict__ outb,
    float* __restrict__ out){
  int b = blockIdx.y; int v0 = blockIdx.x * 8;
  int tid = threadIdx.x;
  __shared__ float hcl[512][8];
  __shared__ float gl[512][9];
  for (int u=0; u<16; ++u){
    int lid = u*256 + tid; int o = lid>>3, vv = lid&7;
    hcl[o][vv] = hc[((size_t)b*512 + o)*VV + v0 + vv];
  }
  __syncthreads();
  float aL0[8], aR0[8], aL1[8], aR1[8];
  #pragma unroll
  for (int u=0;u<8;++u){ aL0[u]=0.f; aR0[u]=0.f; aL1[u]=0.f; aR1[u]=0.f; }
  for (int o=0; o<512; ++o){
    const float* grow = gluT + (size_t)o*1024;
    float g0 = grow[tid], g1 = grow[tid+256], g2 = grow[tid+512], g3 = grow[tid+768];
    float hv[8];
    *(float4*)hv     = *(const float4*)&hcl[o][0];
    *(float4*)(hv+4) = *(const float4*)&hcl[o][4];
    #pragma unroll
    for (int u=0;u<8;++u){
      aL0[u]=fmaf(g0,hv[u],aL0[u]); aL1[u]=fmaf(g1,hv[u],aL1[u]);
      aR0[u]=fmaf(g2,hv[u],aR0[u]); aR1[u]=fmaf(g3,hv[u],aR1[u]);
    }
  }
  float bL0 = glub[tid], bL1 = glub[tid+256], bR0 = glub[tid+512], bR1 = glub[tid+768];
  #pragma unroll
  for (int u=0;u<8;++u){
    gl[tid][u]     = (aL0[u]+bL0)*sigmoidf_(aR0[u]+bR0);
    gl[tid+256][u] = (aL1[u]+bL1)*sigmoidf_(aR1[u]+bR1);
  }
  __syncthreads();
  if (tid < 96){
    int r = tid>>3, vv = tid&7;
    float acc = outb[r];
    for (int q=0; q<512; ++q) acc = fmaf(outT[(size_t)q*12 + r], gl[q][vv], acc);
    out[(size_t)b*6144 + r*512 + v0 + vv] = acc;
  }
}

// ---------------------------------------------------------------------------
extern "C" void kernel_launch(void* const* d_in, const int* in_sizes, int n_in,
                              void* d_out, int out_size, void* d_ws, size_t ws_size,
                              hipStream_t stream){
  const float* x        = (const float*)d_in[0];
  const float* sape     = (const float*)d_in[1];
  const float* tape     = (const float*)d_in[2];
  const float* srpe     = (const float*)d_in[3];
  const float* trpe     = (const float*)d_in[4];
  const float* mask     = (const float*)d_in[7];
  const float* input_w  = (const float*)d_in[8];
  const float* input_b  = (const float*)d_in[9];
  const float* fs0_fc_w = (const float*)d_in[10];
  const float* fs0_fc_b = (const float*)d_in[11];
  const float* fs0_glu_w= (const float*)d_in[12];
  const float* fs0_glu_b= (const float*)d_in[13];
  const float* mus      = (const float*)d_in[14];
  const float* isg      = (const float*)d_in[15];
  const float* xproj_w  = (const float*)d_in[16];
  const float* xproj_b  = (const float*)d_in[17];
  const float* seproj_w = (const float*)d_in[18];
  const float* teproj_w = (const float*)d_in[19];
  const float* ln_g     = (const float*)d_in[20];
  const float* ln_b     = (const float*)d_in[21];
  const float* fs_fc_w  = (const float*)d_in[22];
  const float* fs_fc_b  = (const float*)d_in[23];
  const float* fs_glu_w = (const float*)d_in[24];
  const float* fs_glu_b = (const float*)d_in[25];
  const float* glu_w    = (const float*)d_in[26];
  const float* glu_b    = (const float*)d_in[27];
  const float* out_w    = (const float*)d_in[28];
  const float* out_b    = (const float*)d_in[29];

  float* ws    = (float*)d_ws;
  float* hA    = ws;                          // 6,291,456
  float* hc    = hA    + 6291456;             // 2,097,152
  float* s_part= hc    + 2097152;             // 2,097,152
  float* fwT   = s_part+ 2097152;             //   786,432
  float* gwT   = fwT   + 786432;              //   131,072
  float* gluT  = gwT   + 131072;              //   524,288
  float* outT  = gluT  + 524288;              //     6,144
  float* gi    = outT  + 6144;                //       512
  float* gj    = gi    + 512;                 //       512
  float* Ebuf  = gj    + 512;                 //        96
  float* Fbuf  = Ebuf  + 96;                  //       288
  float* gtr   = Fbuf  + 288;                 //        16 (pad)
  ushort_t* hhiT = (ushort_t*)(gtr + 16);     // 6,291,456 ushorts
  ushort_t* hloT = hhiT + 6291456;            // 6,291,456 ushorts
  ushort_t* Whi  = hloT + 6291456;            //   786,432 ushorts
  ushort_t* Wlo  = Whi  + 786432;             //   786,432 ushorts
  ushort_t* xcat_hi = Wlo + 786432;           //   122,880 ushorts
  ushort_t* xcat_lo = xcat_hi + 122880;       //   122,880 ushorts

  k_prep<<<dim3(2048,11),256,0,stream>>>(fs0_fc_w, fs_fc_w, fs0_glu_w, fs_glu_w,
                                         glu_w, out_w, xproj_w, seproj_w, teproj_w,
                                         xproj_b, fwT, gwT, gluT, outT,
                                         xcat_hi, xcat_lo);
  k_input<<<dim3(96,8),256,0,stream>>>(x, input_w, input_b, hA, hhiT, hloT);
  k_gfs1<<<dim3(16,8,4),256,0,stream>>>(hA, fwT, s_part);
  k_gfs2<<<dim3(16,8),256,0,stream>>>(s_part, fs0_fc_b, gwT, fs0_glu_b, hc, 0);

  for (int l=0; l<3; ++l){
    k_smalls<<<1,512,0,stream>>>(sape, tape, trpe, mus, isg, l, gi, gj, Ebuf, Fbuf, gtr);
    k_W<<<dim3(32,32),256,0,stream>>>(srpe, mask, mus, isg, l, gi, gj, gtr, Whi, Wlo);
    k_stpg<<<dim3(96,4),256,0,stream>>>(hhiT, hloT, Whi, Wlo, Ebuf, Fbuf, hA);
    k_xln2<<<dim3(4,96),256,0,stream>>>(hA, xcat_hi, xcat_lo, sape, tape,
                                        ln_g, ln_b, l, hhiT, hloT);
    k_gfs1<<<dim3(16,8,4),256,0,stream>>>(hA, fwT + (size_t)(l+1)*196608, s_part);
    k_gfs2<<<dim3(16,8),256,0,stream>>>(s_part, fs_fc_b + l*128, gwT + (size_t)(l+1)*32768,
                                        fs_glu_b + l*256, hc, l+1);
  }
  k_final<<<dim3(64,8),256,0,stream>>>(hc, gluT, glu_b, outT, out_b, (float*)d_out);
}